// Round 5
// baseline (1881.358 us; speedup 1.0000x reference)
//
#include <hip/hip_runtime.h>

// LIIF render, fully fused, fp16 MFMA. Round 8: wave-owns-rows restructure.
// R4-R7 post-mortem: every attempt to add operand double-buffers inside the
// 4-wave/128-row structure spilled (FETCH/WRITE ballooned), even at 48
// operand regs. Proven no-spill fixed point = R3's shape: acc 128 (forced
// into AGPRs) + <=48 arch operand regs + rolled loops. Pipelining must be
// built AROUND that, not against it.
// Round-8 restructure:
//  - Each 64-thread block (1 wave) owns 32 query rows END-TO-END (all 256
//    out-features), instead of a 64-feature slice of 128 shared rows.
//    -> wave reads/writes only its own LDS rows: ZERO __syncthreads in the
//    kernel (per-wave LDS ops are hardware-ordered). 16.9 KB LDS/block ->
//    9 waves/CU, all unsynchronized -> real cross-wave latency hiding.
//  - All waves on a CU stream the SAME weight sequence (was: 4 disjoint
//    32KB slices thrashing the 32KB L1) -> A-loads L1-hit after the leader.
//  - acc[16][2] = 128 regs (the R3-proven AGPR shape). Arch operands =
//    exactly R3's 48: aP[4]/aQ[4] ping-pong at 4-load granularity (one
//    8-MFMA burst = ~155cy ahead of use) + bP[2]/bQ[2] (B prefetched a
//    full k-step ~700cy ahead). k-loop rolled (#pragma unroll 1).
//  - B loaded once per k-step for all 16 m-tiles: LDS reads 64 -> 16 per
//    layer-wave. In-place layer update safe: all B reads precede the
//    epilogue writes in wave program order.
//  - Numerics identical (same per-output k-accumulation order).
// Gates: FETCH<=30MB/WRITE<=40MB (no spill) -> dur<606 -> MfmaUtil 45-60%.

typedef _Float16 f16;
typedef _Float16 f16x8 __attribute__((ext_vector_type(8)));
typedef _Float16 f16x4 __attribute__((ext_vector_type(4)));
typedef float    f32x4 __attribute__((ext_vector_type(4)));

#define MFMA(a, b, c) __builtin_amdgcn_mfma_f32_16x16x32_f16((a), (b), (c), 0, 0, 0)

constexpr int HF = 64, WF = 64;         // feature map dims
constexpr int HO = 256, WO = 256;       // output dims
constexpr int Q = HO * WO;              // 65536 queries per image
constexpr int D = 256;                  // hidden width
constexpr int K0P = 96;                 // input dim 68 padded to 96 (3 k-steps)
constexpr int STR = 264;                // LDS row stride (halves)
constexpr int RW = 32;                  // query rows per wave/block

// workspace layout (bytes)
constexpr size_t OFF_FEAT = 0;                        // 4*4096*64*2 = 2 MiB
constexpr size_t OFF_W0   = 2097152;                  // 256*96*2
constexpr size_t OFF_W1   = OFF_W0 + 256 * 96 * 2;    // 256*256*2
constexpr size_t OFF_W2   = OFF_W1 + 256 * 256 * 2;
constexpr size_t OFF_W3   = OFF_W2 + 256 * 256 * 2;
constexpr size_t OFF_W4   = OFF_W3 + 256 * 256 * 2;   // 16*256*2

// (N,C,Hf,Wf) fp32 -> (N, Hf*Wf, C) fp16 so a gather row is 128 B contiguous.
__global__ void prep_feat(const float* __restrict__ f, f16* __restrict__ ft) {
  int idx = blockIdx.x * 256 + threadIdx.x;          // 1,048,576 total
  int c = idx & 63, p = (idx >> 6) & 4095, n = idx >> 18;
  ft[idx] = (f16)f[((((size_t)n << 6) | c) << 12) | p];
}

// w (K x N) fp32 -> wt (Npad x Kpad) fp16, zero-padded.
__global__ void prep_w(const float* __restrict__ w, f16* __restrict__ wt,
                       int K, int N, int Kpad, int Npad) {
  int idx = blockIdx.x * 256 + threadIdx.x;
  if (idx >= Npad * Kpad) return;
  int k = idx % Kpad, n = idx / Kpad;
  wt[idx] = (f16)((k < K && n < N) ? w[k * N + n] : 0.0f);
}

// Geometry for query q, tap (vx, vy): feature pixel p and rel coords.
__device__ __forceinline__ void tap_geom(int q, float vx, float vy,
                                         int& p, float& rel0, float& rel1) {
  int qy = q >> 8, qx = q & (WO - 1);
  float cy0 = (float)(2 * qy + 1) * (1.0f / HO) - 1.0f;
  float cx0 = (float)(2 * qx + 1) * (1.0f / WO) - 1.0f;
  float cy = cy0 + vx * (1.0f / HF) + 1e-6f;
  float cx = cx0 + vy * (1.0f / WF) + 1e-6f;
  cy = fminf(fmaxf(cy, -1.0f + 1e-6f), 1.0f - 1e-6f);
  cx = fminf(fmaxf(cx, -1.0f + 1e-6f), 1.0f - 1e-6f);
  int iy = (int)rintf(((cy + 1.0f) * (float)HF - 1.0f) * 0.5f);  // rndne == jnp.round
  int ix = (int)rintf(((cx + 1.0f) * (float)WF - 1.0f) * 0.5f);
  iy = min(max(iy, 0), HF - 1);
  ix = min(max(ix, 0), WF - 1);
  p = (iy << 6) | ix;
  rel0 = (cy0 - ((float)(2 * iy + 1) * (1.0f / HF) - 1.0f)) * (float)HF;
  rel1 = (cx0 - ((float)(2 * ix + 1) * (1.0f / WF) - 1.0f)) * (float)WF;
}

// Blend weight for tap t, query q: preds[t] pairs with areas[3-t].
__device__ __forceinline__ float blend_wt(int q, int t) {
  float a[4], tot = 0.0f;
#pragma unroll
  for (int u = 0; u < 4; ++u) {
    int p; float r0, r1;
    tap_geom(q, (u & 2) ? 1.0f : -1.0f, (u & 1) ? 1.0f : -1.0f, p, r0, r1);
    a[u] = fabsf(r0 * r1) + 1e-9f;
    tot += a[u];
  }
  float sel = (t == 0) ? a[3] : (t == 1) ? a[2] : (t == 2) ? a[1] : a[0];
  return sel / tot;
}

// One hidden layer: ALL 256 out-features for this wave's 32 rows, in place.
// MFMA m = out-feature tile M (16 tiles), n = query rows (2 tiles of 16).
// acc[16][2] f32x4 = 128 regs (AGPR side, the R3-proven shape).
// Rolled k-loop; per k-step: 4 groups of {prefetch next A group (4x16B);
// 8 MFMAs} -> every A load sits one ~155cy burst ahead of its use; B for
// step s+1 loads during group 2 (~700cy ahead). Wave-private rows -> the
// epilogue overwrite needs no barrier (per-wave LDS ordering).
template <int KSTEPS, int KPAD>
__device__ __forceinline__ void mlp_layer(f16* X, const f16* __restrict__ wt,
                                          const float* __restrict__ bv,
                                          int col, int quad) {
  f32x4 acc[16][2];
#pragma unroll
  for (int M = 0; M < 16; ++M) { acc[M][0] = 0.0f; acc[M][1] = 0.0f; }

  const f16* ap = wt + col * KPAD + quad * 8;   // A[m=M*16+col][k=s*32+quad*8]
  const f16* bp = X + col * STR + quad * 8;     // B[n=nt*16+col][k]

  f16x8 aP[4], aQ[4], bP[2], bQ[2];
#pragma unroll
  for (int mt = 0; mt < 4; ++mt)
    aP[mt] = *(const f16x8*)(ap + mt * 16 * KPAD);
  bP[0] = *(const f16x8*)(bp);
  bP[1] = *(const f16x8*)(bp + 16 * STR);

#pragma unroll 1
  for (int s = 0; s < KSTEPS; ++s) {
    // G0: burst M0-3 (aP); prefetch M4-7 into aQ
#pragma unroll
    for (int mt = 0; mt < 4; ++mt)
      aQ[mt] = *(const f16x8*)(ap + (4 + mt) * 16 * KPAD + s * 32);
    __builtin_amdgcn_s_setprio(1);
#pragma unroll
    for (int mt = 0; mt < 4; ++mt) {
      acc[mt][0] = MFMA(aP[mt], bP[0], acc[mt][0]);
      acc[mt][1] = MFMA(aP[mt], bP[1], acc[mt][1]);
    }
    __builtin_amdgcn_s_setprio(0);
    // G1: burst M4-7 (aQ); prefetch M8-11 into aP
#pragma unroll
    for (int mt = 0; mt < 4; ++mt)
      aP[mt] = *(const f16x8*)(ap + (8 + mt) * 16 * KPAD + s * 32);
    __builtin_amdgcn_s_setprio(1);
#pragma unroll
    for (int mt = 0; mt < 4; ++mt) {
      acc[4 + mt][0] = MFMA(aQ[mt], bP[0], acc[4 + mt][0]);
      acc[4 + mt][1] = MFMA(aQ[mt], bP[1], acc[4 + mt][1]);
    }
    __builtin_amdgcn_s_setprio(0);
    // G2: burst M8-11 (aP); prefetch M12-15 into aQ and B(s+1) into bQ
#pragma unroll
    for (int mt = 0; mt < 4; ++mt)
      aQ[mt] = *(const f16x8*)(ap + (12 + mt) * 16 * KPAD + s * 32);
    if (s + 1 < KSTEPS) {
      bQ[0] = *(const f16x8*)(bp + (s + 1) * 32);
      bQ[1] = *(const f16x8*)(bp + 16 * STR + (s + 1) * 32);
    }
    __builtin_amdgcn_s_setprio(1);
#pragma unroll
    for (int mt = 0; mt < 4; ++mt) {
      acc[8 + mt][0] = MFMA(aP[mt], bP[0], acc[8 + mt][0]);
      acc[8 + mt][1] = MFMA(aP[mt], bP[1], acc[8 + mt][1]);
    }
    __builtin_amdgcn_s_setprio(0);
    // G3: burst M12-15 (aQ); prefetch M0-3 @ s+1 into aP
    if (s + 1 < KSTEPS) {
#pragma unroll
      for (int mt = 0; mt < 4; ++mt)
        aP[mt] = *(const f16x8*)(ap + mt * 16 * KPAD + (s + 1) * 32);
    }
    __builtin_amdgcn_s_setprio(1);
#pragma unroll
    for (int mt = 0; mt < 4; ++mt) {
      acc[12 + mt][0] = MFMA(aQ[mt], bP[0], acc[12 + mt][0]);
      acc[12 + mt][1] = MFMA(aQ[mt], bP[1], acc[12 + mt][1]);
    }
    __builtin_amdgcn_s_setprio(0);
    if (s + 1 < KSTEPS) { bP[0] = bQ[0]; bP[1] = bQ[1]; }
  }

  // Epilogue: bias + relu, write back in place. All B reads of this layer
  // are already complete in program order; rows are wave-private.
  // D: row(m=feat) = M*16 + quad*4 + i, col(n) = nt*16 + col.
#pragma unroll
  for (int M = 0; M < 16; ++M) {
    float4 bb = *(const float4*)(bv + M * 16 + quad * 4);
#pragma unroll
    for (int nt = 0; nt < 2; ++nt) {
      f16x4 y;
      y[0] = (f16)fmaxf(acc[M][nt][0] + bb.x, 0.0f);
      y[1] = (f16)fmaxf(acc[M][nt][1] + bb.y, 0.0f);
      y[2] = (f16)fmaxf(acc[M][nt][2] + bb.z, 0.0f);
      y[3] = (f16)fmaxf(acc[M][nt][3] + bb.w, 0.0f);
      *(f16x4*)(X + (nt * 16 + col) * STR + M * 16 + quad * 4) = y;
    }
  }
}

__global__ __launch_bounds__(64, 2) void liif_main(
    const f16* __restrict__ featT,
    const f16* __restrict__ wt0, const f16* __restrict__ wt1,
    const f16* __restrict__ wt2, const f16* __restrict__ wt3,
    const f16* __restrict__ wt4,
    const float* __restrict__ b0, const float* __restrict__ b1,
    const float* __restrict__ b2, const float* __restrict__ b3,
    const float* __restrict__ b4, float* __restrict__ out) {
  __shared__ __attribute__((aligned(16))) f16 X[RW * STR];   // 16.9 KB
  const int lane = threadIdx.x;                  // one wave per block
  const int row0 = blockIdx.x * RW;              // rows = n*Q + q, 32 per block
  const int n = row0 >> 16;
  const int q0 = row0 & (Q - 1);
  const int col = lane & 15, quad = lane >> 4;

  float oacc[2][4] = {{0, 0, 0, 0}, {0, 0, 0, 0}};
  float bias4[4];
#pragma unroll
  for (int i = 0; i < 4; ++i) bias4[i] = (i < 3) ? b4[i] : 0.0f;

#pragma unroll 1
  for (int t = 0; t < 4; ++t) {
    const float vx = (t & 2) ? 1.0f : -1.0f;
    const float vy = (t & 1) ? 1.0f : -1.0f;

    // ---- gather X0: 64 feat + rel(2) + rel_cell(2), pad to 96 ----
    // Wave-private rows; per-wave LDS ordering makes this safe without any
    // barrier (prior tap's reads of X precede these writes in program order).
    {
      const int gr = lane >> 1, hf = lane & 1;   // 2 lanes per row, 64 B each
      int p; float r0, r1;
      tap_geom(q0 + gr, vx, vy, p, r0, r1);
      const f16x8* src = (const f16x8*)(featT + (((size_t)n << 12) + p) * 64 + hf * 32);
      f16x8* dst = (f16x8*)(X + gr * STR + hf * 32);
      dst[0] = src[0]; dst[1] = src[1]; dst[2] = src[2]; dst[3] = src[3];
      if (lane < RW) {
        int p2; float s0, s1;
        tap_geom(q0 + lane, vx, vy, p2, s0, s1);
        f16* xr = X + lane * STR;
        f16x4 relv = {(f16)s0, (f16)s1, (f16)0.5f, (f16)0.5f};
        *(f16x4*)(xr + 64) = relv;
        f16x4 z4 = {0, 0, 0, 0};
        f16x8 z8 = {0, 0, 0, 0, 0, 0, 0, 0};
        *(f16x4*)(xr + 68) = z4;     // zero pad cols 68..95
        *(f16x8*)(xr + 72) = z8;
        *(f16x8*)(xr + 80) = z8;
        *(f16x8*)(xr + 88) = z8;
      }
    }

    mlp_layer<3, K0P>(X, wt0, b0, col, quad);
    mlp_layer<8, D>(X, wt1, b1, col, quad);
    mlp_layer<8, D>(X, wt2, b2, col, quad);
    mlp_layer<8, D>(X, wt3, b3, col, quad);

    // ---- final layer 256 -> 16 (3 real feats) for the wave's 32 queries ----
    f32x4 facc[2];
    facc[0] = 0.0f; facc[1] = 0.0f;
    {
      const f16* ap = wt4 + col * D + quad * 8;        // A[m=feat=col][k]
      const f16* bp = X + col * STR + quad * 8;        // B[n=query rows]
#pragma unroll 1
      for (int s = 0; s < 8; ++s) {
        f16x8 a = *(const f16x8*)(ap + s * 32);
        f16x8 bq0 = *(const f16x8*)(bp + s * 32);
        f16x8 bq1 = *(const f16x8*)(bp + 16 * STR + s * 32);
        facc[0] = MFMA(a, bq0, facc[0]);
        facc[1] = MFMA(a, bq1, facc[1]);
      }
    }
    // D: row=feat=quad*4+i, col=query. Blend into oacc.
#pragma unroll
    for (int nt = 0; nt < 2; ++nt) {
      int q = q0 + nt * 16 + col;
      float w = blend_wt(q, t);
#pragma unroll
      for (int i = 0; i < 4; ++i) oacc[nt][i] += (facc[nt][i] + bias4[i]) * w;
    }
  }

  // out[n][c][q]; lanes with quad==0 hold feats 0..3 (3 real) for their queries
  if (quad == 0) {
#pragma unroll
    for (int nt = 0; nt < 2; ++nt) {
      int q = q0 + nt * 16 + col;
#pragma unroll
      for (int c = 0; c < 3; ++c)
        out[(((size_t)(n * 3 + c)) << 16) + q] = oacc[nt][c];
    }
  }
}

extern "C" void kernel_launch(void* const* d_in, const int* in_sizes, int n_in,
                              void* d_out, int out_size, void* d_ws, size_t ws_size,
                              hipStream_t stream) {
  const float* feat = (const float*)d_in[0];
  const float* w0 = (const float*)d_in[1];
  const float* b0 = (const float*)d_in[2];
  const float* w1 = (const float*)d_in[3];
  const float* b1 = (const float*)d_in[4];
  const float* w2 = (const float*)d_in[5];
  const float* b2 = (const float*)d_in[6];
  const float* w3 = (const float*)d_in[7];
  const float* b3 = (const float*)d_in[8];
  const float* w4 = (const float*)d_in[9];
  const float* b4 = (const float*)d_in[10];

  char* ws = (char*)d_ws;
  f16* featT = (f16*)(ws + OFF_FEAT);
  f16* wt0 = (f16*)(ws + OFF_W0);
  f16* wt1 = (f16*)(ws + OFF_W1);
  f16* wt2 = (f16*)(ws + OFF_W2);
  f16* wt3 = (f16*)(ws + OFF_W3);
  f16* wt4 = (f16*)(ws + OFF_W4);

  prep_feat<<<4096, 256, 0, stream>>>(feat, featT);
  prep_w<<<(256 * 96 + 255) / 256, 256, 0, stream>>>(w0, wt0, 68, 256, 96, 256);
  prep_w<<<256, 256, 0, stream>>>(w1, wt1, 256, 256, 256, 256);
  prep_w<<<256, 256, 0, stream>>>(w2, wt2, 256, 256, 256, 256);
  prep_w<<<256, 256, 0, stream>>>(w3, wt3, 256, 256, 256, 256);
  prep_w<<<(16 * 256 + 255) / 256, 256, 0, stream>>>(w4, wt4, 256, 3, 256, 16);

  liif_main<<<Q * 4 / RW, 64, 0, stream>>>(featT, wt0, wt1, wt2, wt3, wt4,
                                           b0, b1, b2, b3, b4, (float*)d_out);
}

// Round 7
// 993.085 us; speedup vs baseline: 1.8945x; 1.8945x over previous
//
#include <hip/hip_runtime.h>

// LIIF render, fully fused, fp16 MFMA. Round 9 (resubmit — R6 bench was a
// GPUAcquisitionTimeout, kernel never ran): occupancy lever (R=64),
// k-loop schedule byte-identical to the proven Round-3 kernel.
// R4-R8 post-mortem: five software-pipelining variants, five spills -- my
// register estimates run ~50 regs low vs the allocator (addressing, copies,
// scheduler-extended live ranges). Only verified no-spill point: R3's shape
// (rolled loop, single 'a' frag, one b[] array, acc->AGPR, demand ~2/3 of
// cap). So: stop touching the loop; change what the allocator doesn't see.
// Round-9 change: block row-tile R 128 -> 64.
//  - LDS 67.6 -> 33.8 KB  => 3 blocks/CU (was 2): +50% TLP, 2->3 waves/SIMD,
//    all extra waves in DIFFERENT blocks -> barrier drains overlap.
//  - __launch_bounds__(256,3): reg cap 170/wave. Demand: acc[4][4]=64
//    (AGPR-eligible) + b[4]=16 + a=4 + misc~50 ~= 135 -> 20% margin, same
//    relative slack as proven-R3 (226/256). No ping-pong, no setprio.
//  - Cost accepted: weight L2 traffic 2x (~7 GB total ~= 16 TB/s, under the
//    34.5 TB/s L2 ceiling); slightly worse load:MFMA issue ratio -- both
//    slack at MfmaUtil 34%.
//  - Numerics identical: same per-output k order. absmax must stay 0.00390625.
// Gates: FETCH<=25MB/WRITE<=40MB (no spill) -> Occupancy ~33% -> dur<606.

typedef _Float16 f16;
typedef _Float16 f16x8 __attribute__((ext_vector_type(8)));
typedef _Float16 f16x4 __attribute__((ext_vector_type(4)));
typedef float    f32x4 __attribute__((ext_vector_type(4)));

#define MFMA(a, b, c) __builtin_amdgcn_mfma_f32_16x16x32_f16((a), (b), (c), 0, 0, 0)

constexpr int HF = 64, WF = 64;         // feature map dims
constexpr int HO = 256, WO = 256;       // output dims
constexpr int Q = HO * WO;              // 65536 queries per image
constexpr int D = 256;                  // hidden width
constexpr int K0P = 96;                 // input dim 68 padded to 96 (3 k-steps)
constexpr int STR = 264;                // LDS row stride (halves)
constexpr int R = 64;                   // query rows per block (was 128)

// workspace layout (bytes)
constexpr size_t OFF_FEAT = 0;                        // 4*4096*64*2 = 2 MiB
constexpr size_t OFF_W0   = 2097152;                  // 256*96*2
constexpr size_t OFF_W1   = OFF_W0 + 256 * 96 * 2;    // 256*256*2
constexpr size_t OFF_W2   = OFF_W1 + 256 * 256 * 2;
constexpr size_t OFF_W3   = OFF_W2 + 256 * 256 * 2;
constexpr size_t OFF_W4   = OFF_W3 + 256 * 256 * 2;   // 16*256*2

// (N,C,Hf,Wf) fp32 -> (N, Hf*Wf, C) fp16 so a gather row is 128 B contiguous.
__global__ void prep_feat(const float* __restrict__ f, f16* __restrict__ ft) {
  int idx = blockIdx.x * 256 + threadIdx.x;          // 1,048,576 total
  int c = idx & 63, p = (idx >> 6) & 4095, n = idx >> 18;
  ft[idx] = (f16)f[((((size_t)n << 6) | c) << 12) | p];
}

// w (K x N) fp32 -> wt (Npad x Kpad) fp16, zero-padded.
__global__ void prep_w(const float* __restrict__ w, f16* __restrict__ wt,
                       int K, int N, int Kpad, int Npad) {
  int idx = blockIdx.x * 256 + threadIdx.x;
  if (idx >= Npad * Kpad) return;
  int k = idx % Kpad, n = idx / Kpad;
  wt[idx] = (f16)((k < K && n < N) ? w[k * N + n] : 0.0f);
}

// Geometry for query q, tap (vx, vy): feature pixel p and rel coords.
__device__ __forceinline__ void tap_geom(int q, float vx, float vy,
                                         int& p, float& rel0, float& rel1) {
  int qy = q >> 8, qx = q & (WO - 1);
  float cy0 = (float)(2 * qy + 1) * (1.0f / HO) - 1.0f;
  float cx0 = (float)(2 * qx + 1) * (1.0f / WO) - 1.0f;
  float cy = cy0 + vx * (1.0f / HF) + 1e-6f;
  float cx = cx0 + vy * (1.0f / WF) + 1e-6f;
  cy = fminf(fmaxf(cy, -1.0f + 1e-6f), 1.0f - 1e-6f);
  cx = fminf(fmaxf(cx, -1.0f + 1e-6f), 1.0f - 1e-6f);
  int iy = (int)rintf(((cy + 1.0f) * (float)HF - 1.0f) * 0.5f);  // rndne == jnp.round
  int ix = (int)rintf(((cx + 1.0f) * (float)WF - 1.0f) * 0.5f);
  iy = min(max(iy, 0), HF - 1);
  ix = min(max(ix, 0), WF - 1);
  p = (iy << 6) | ix;
  rel0 = (cy0 - ((float)(2 * iy + 1) * (1.0f / HF) - 1.0f)) * (float)HF;
  rel1 = (cx0 - ((float)(2 * ix + 1) * (1.0f / WF) - 1.0f)) * (float)WF;
}

// Blend weight for tap t, query q: preds[t] pairs with areas[3-t].
__device__ __forceinline__ float blend_wt(int q, int t) {
  float a[4], tot = 0.0f;
#pragma unroll
  for (int u = 0; u < 4; ++u) {
    int p; float r0, r1;
    tap_geom(q, (u & 2) ? 1.0f : -1.0f, (u & 1) ? 1.0f : -1.0f, p, r0, r1);
    a[u] = fabsf(r0 * r1) + 1e-9f;
    tot += a[u];
  }
  float sel = (t == 0) ? a[3] : (t == 1) ? a[2] : (t == 2) ? a[1] : a[0];
  return sel / tot;
}

// One hidden layer on the shared 64-row tile, in place. R3's exact schedule
// at half the n-extent: m = out-feature (wave owns feats [wv*64, wv*64+64)),
// n = 64 query rows (4 tiles). acc[4][4]=64 regs; b[4]=16; single 'a' frag.
template <int KSTEPS, int KPAD>
__device__ __forceinline__ void mlp_layer(f16* X, const f16* __restrict__ wt,
                                          const float* __restrict__ bv,
                                          int wv, int col, int quad) {
  f32x4 acc[4][4];
#pragma unroll
  for (int mt = 0; mt < 4; ++mt)
#pragma unroll
    for (int nt = 0; nt < 4; ++nt) acc[mt][nt] = 0.0f;

  const f16* ap = wt + (wv * 64 + col) * KPAD + quad * 8;  // A[m=col+16mt][k]
  const f16* bp = X + col * STR + quad * 8;                // B[n=col+16nt][k]
#pragma unroll 1
  for (int s = 0; s < KSTEPS; ++s) {
    f16x8 b[4];
#pragma unroll
    for (int nt = 0; nt < 4; ++nt)
      b[nt] = *(const f16x8*)(bp + s * 32 + nt * 16 * STR);
#pragma unroll
    for (int mt = 0; mt < 4; ++mt) {
      f16x8 a = *(const f16x8*)(ap + s * 32 + mt * 16 * KPAD);
#pragma unroll
      for (int nt = 0; nt < 4; ++nt) acc[mt][nt] = MFMA(a, b[nt], acc[mt][nt]);
    }
  }
  __syncthreads();   // all reads of X done before overwrite
  // D: row(m=feat) = mt*16 + quad*4 + i, col(n=query) = nt*16 + col.
#pragma unroll
  for (int mt = 0; mt < 4; ++mt) {
    float4 bb = *(const float4*)(bv + wv * 64 + mt * 16 + quad * 4);
#pragma unroll
    for (int nt = 0; nt < 4; ++nt) {
      f16x4 y;
      y[0] = (f16)fmaxf(acc[mt][nt][0] + bb.x, 0.0f);
      y[1] = (f16)fmaxf(acc[mt][nt][1] + bb.y, 0.0f);
      y[2] = (f16)fmaxf(acc[mt][nt][2] + bb.z, 0.0f);
      y[3] = (f16)fmaxf(acc[mt][nt][3] + bb.w, 0.0f);
      *(f16x4*)(X + (nt * 16 + col) * STR + wv * 64 + mt * 16 + quad * 4) = y;
    }
  }
  __syncthreads();
}

__global__ __launch_bounds__(256, 3) void liif_main(
    const f16* __restrict__ featT,
    const f16* __restrict__ wt0, const f16* __restrict__ wt1,
    const f16* __restrict__ wt2, const f16* __restrict__ wt3,
    const f16* __restrict__ wt4,
    const float* __restrict__ b0, const float* __restrict__ b1,
    const float* __restrict__ b2, const float* __restrict__ b3,
    const float* __restrict__ b4, float* __restrict__ out) {
  __shared__ __attribute__((aligned(16))) f16 X[R * STR];   // 33.8 KB
  const int tid = threadIdx.x;
  const int wv = tid >> 6;
  const int lane = tid & 63;
  const int row0 = blockIdx.x * R;               // rows = n*Q + q, 64 per block
  const int n = row0 >> 16;
  const int q0 = row0 & (Q - 1);
  const int col = lane & 15, quad = lane >> 4;

  float oacc[4] = {0, 0, 0, 0};
  float bias4[4];
#pragma unroll
  for (int i = 0; i < 4; ++i) bias4[i] = (i < 3) ? b4[i] : 0.0f;

#pragma unroll 1
  for (int t = 0; t < 4; ++t) {
    const float vx = (t & 2) ? 1.0f : -1.0f;
    const float vy = (t & 1) ? 1.0f : -1.0f;

    __syncthreads();   // previous tap's reads of X complete
    // ---- gather X0: 64 feat + rel(2) + rel_cell(2), pad to 96 ----
    {
      const int gr = tid >> 2, hf = tid & 3;   // 4 threads per row, 32 B each
      int p; float r0, r1;
      tap_geom(q0 + gr, vx, vy, p, r0, r1);
      const f16x8* src = (const f16x8*)(featT + (((size_t)n << 12) + p) * 64 + hf * 16);
      f16x8* dst = (f16x8*)(X + gr * STR + hf * 16);
      dst[0] = src[0]; dst[1] = src[1];
      if (tid < R) {
        int p2; float s0, s1;
        tap_geom(q0 + tid, vx, vy, p2, s0, s1);
        f16* xr = X + tid * STR;
        f16x4 relv = {(f16)s0, (f16)s1, (f16)0.5f, (f16)0.5f};
        *(f16x4*)(xr + 64) = relv;
        f16x4 z4 = {0, 0, 0, 0};
        f16x8 z8 = {0, 0, 0, 0, 0, 0, 0, 0};
        *(f16x4*)(xr + 68) = z4;     // zero pad cols 68..95
        *(f16x8*)(xr + 72) = z8;
        *(f16x8*)(xr + 80) = z8;
        *(f16x8*)(xr + 88) = z8;
      }
    }
    __syncthreads();

    mlp_layer<3, K0P>(X, wt0, b0, wv, col, quad);
    mlp_layer<8, D>(X, wt1, b1, wv, col, quad);
    mlp_layer<8, D>(X, wt2, b2, wv, col, quad);
    mlp_layer<8, D>(X, wt3, b3, wv, col, quad);

    // ---- final layer 256 -> 16 (3 real feats); wave handles its 16 queries ----
    f32x4 facc;
    facc = 0.0f;
    {
      const f16* ap = wt4 + col * D + quad * 8;              // A[m=feat=col][k]
      const f16* bp = X + (wv * 16 + col) * STR + quad * 8;  // B[n=query]
#pragma unroll 1
      for (int s = 0; s < 8; ++s) {
        f16x8 a = *(const f16x8*)(ap + s * 32);
        f16x8 bq = *(const f16x8*)(bp + s * 32);
        facc = MFMA(a, bq, facc);
      }
    }
    // D: row=feat=quad*4+i, col=query. Blend into oacc.
    {
      int q = q0 + wv * 16 + col;
      float w = blend_wt(q, t);
#pragma unroll
      for (int i = 0; i < 4; ++i) oacc[i] += (facc[i] + bias4[i]) * w;
    }
  }

  // out[n][c][q]; lanes with quad==0 hold feats 0..3 (3 real) for their queries
  if (quad == 0) {
    int q = q0 + wv * 16 + col;
#pragma unroll
    for (int c = 0; c < 3; ++c)
      out[(((size_t)(n * 3 + c)) << 16) + q] = oacc[c];
  }
}

extern "C" void kernel_launch(void* const* d_in, const int* in_sizes, int n_in,
                              void* d_out, int out_size, void* d_ws, size_t ws_size,
                              hipStream_t stream) {
  const float* feat = (const float*)d_in[0];
  const float* w0 = (const float*)d_in[1];
  const float* b0 = (const float*)d_in[2];
  const float* w1 = (const float*)d_in[3];
  const float* b1 = (const float*)d_in[4];
  const float* w2 = (const float*)d_in[5];
  const float* b2 = (const float*)d_in[6];
  const float* w3 = (const float*)d_in[7];
  const float* b3 = (const float*)d_in[8];
  const float* w4 = (const float*)d_in[9];
  const float* b4 = (const float*)d_in[10];

  char* ws = (char*)d_ws;
  f16* featT = (f16*)(ws + OFF_FEAT);
  f16* wt0 = (f16*)(ws + OFF_W0);
  f16* wt1 = (f16*)(ws + OFF_W1);
  f16* wt2 = (f16*)(ws + OFF_W2);
  f16* wt3 = (f16*)(ws + OFF_W3);
  f16* wt4 = (f16*)(ws + OFF_W4);

  prep_feat<<<4096, 256, 0, stream>>>(feat, featT);
  prep_w<<<(256 * 96 + 255) / 256, 256, 0, stream>>>(w0, wt0, 68, 256, 96, 256);
  prep_w<<<256, 256, 0, stream>>>(w1, wt1, 256, 256, 256, 256);
  prep_w<<<256, 256, 0, stream>>>(w2, wt2, 256, 256, 256, 256);
  prep_w<<<256, 256, 0, stream>>>(w3, wt3, 256, 256, 256, 256);
  prep_w<<<(16 * 256 + 255) / 256, 256, 0, stream>>>(w4, wt4, 256, 3, 256, 16);

  liif_main<<<Q * 4 / R, 256, 0, stream>>>(featT, wt0, wt1, wt2, wt3, wt4,
                                           b0, b1, b2, b3, b4, (float*)d_out);
}

// Round 8
// 588.532 us; speedup vs baseline: 3.1967x; 1.6874x over previous
//
#include <hip/hip_runtime.h>

// LIIF render, fully fused, fp16 MFMA. Round 10: A-prefetch across
// lgkm-relaxed barriers, on the verified R3 (606us) structure.
// R9 post-mortem: occupancy 22->32% yet MfmaUtil 34->20, dur 993. Overhead
// per layer-interval ~2.3x the MFMA work (solved from the R3/R9 util pair).
// Corrected model: true FLOP efficiency = 195TF/2075TF = 9.4% (MfmaUtil is
// NOT FLOP fraction); the A(weight) stream hits the ~56B/cy per-CU L2
// ceiling during k-loops (8 waves x 4KB per 620cy step = 52B/cy) because
// __syncthreads' vmcnt(0) drain forces every wave to re-issue A-loads in
// lockstep after each barrier -> queueing -> collective stall.
// Round-10 changes (R3 base, bit-identical numerics):
//  - All __syncthreads -> {s_waitcnt lgkmcnt(0); s_barrier}: LDS hazards
//    only need lgkm ordering; GLOBAL loads stay in flight across barriers
//    (learn_hip 8-phase raw-barrier pattern).
//  - Chained A-prefetch (+8 arch regs): each layer issues the NEXT layer's
//    s=0 mt=0,1 weight frags BEFORE its pre-epilogue barrier; consumed as
//    the first 16 MFMAs after the next barrier (~310cy of immediate work
//    while mt=2,3 loads complete). Final layer gets s=0,1 frags; tap end
//    re-prefetches layer-0 frags for the next tap.
// Register risk is THE failure mode (R4-R8): true arch demand ~100 (R9
// showed VGPR=84; 128 is granularity), +8 should hold at the 128 cap.
// Gates: FETCH<=15MB/WRITE<=40MB & VGPR 128 (no spill) -> dur ~500-555,
// MfmaUtil 38-44. absmax must stay exactly 0.00390625.

typedef _Float16 f16;
typedef _Float16 f16x8 __attribute__((ext_vector_type(8)));
typedef _Float16 f16x4 __attribute__((ext_vector_type(4)));
typedef float    f32x4 __attribute__((ext_vector_type(4)));

#define MFMA(a, b, c) __builtin_amdgcn_mfma_f32_16x16x32_f16((a), (b), (c), 0, 0, 0)

constexpr int HF = 64, WF = 64;         // feature map dims
constexpr int HO = 256, WO = 256;       // output dims
constexpr int Q = HO * WO;              // 65536 queries per image
constexpr int D = 256;                  // hidden width
constexpr int K0P = 96;                 // input dim 68 padded to 96 (3 k-steps)
constexpr int STR = 264;                // LDS row stride (halves)
constexpr int R = 128;                  // query rows per block

// workspace layout (bytes)
constexpr size_t OFF_FEAT = 0;                        // 4*4096*64*2 = 2 MiB
constexpr size_t OFF_W0   = 2097152;                  // 256*96*2
constexpr size_t OFF_W1   = OFF_W0 + 256 * 96 * 2;    // 256*256*2
constexpr size_t OFF_W2   = OFF_W1 + 256 * 256 * 2;
constexpr size_t OFF_W3   = OFF_W2 + 256 * 256 * 2;
constexpr size_t OFF_W4   = OFF_W3 + 256 * 256 * 2;   // 16*256*2

// lgkm-only barrier: waits LDS ops (the actual hazard) but lets global
// loads (A-prefetch) stay in flight across the barrier. The asm's memory
// clobber pins LDS-op ordering at compile time; s_barrier syncs the block.
__device__ __forceinline__ void bar() {
  asm volatile("s_waitcnt lgkmcnt(0)" ::: "memory");
  __builtin_amdgcn_s_barrier();
}

// (N,C,Hf,Wf) fp32 -> (N, Hf*Wf, C) fp16 so a gather row is 128 B contiguous.
__global__ void prep_feat(const float* __restrict__ f, f16* __restrict__ ft) {
  int idx = blockIdx.x * 256 + threadIdx.x;          // 1,048,576 total
  int c = idx & 63, p = (idx >> 6) & 4095, n = idx >> 18;
  ft[idx] = (f16)f[((((size_t)n << 6) | c) << 12) | p];
}

// w (K x N) fp32 -> wt (Npad x Kpad) fp16, zero-padded.
__global__ void prep_w(const float* __restrict__ w, f16* __restrict__ wt,
                       int K, int N, int Kpad, int Npad) {
  int idx = blockIdx.x * 256 + threadIdx.x;
  if (idx >= Npad * Kpad) return;
  int k = idx % Kpad, n = idx / Kpad;
  wt[idx] = (f16)((k < K && n < N) ? w[k * N + n] : 0.0f);
}

// Geometry for query q, tap (vx, vy): feature pixel p and rel coords.
__device__ __forceinline__ void tap_geom(int q, float vx, float vy,
                                         int& p, float& rel0, float& rel1) {
  int qy = q >> 8, qx = q & (WO - 1);
  float cy0 = (float)(2 * qy + 1) * (1.0f / HO) - 1.0f;
  float cx0 = (float)(2 * qx + 1) * (1.0f / WO) - 1.0f;
  float cy = cy0 + vx * (1.0f / HF) + 1e-6f;
  float cx = cx0 + vy * (1.0f / WF) + 1e-6f;
  cy = fminf(fmaxf(cy, -1.0f + 1e-6f), 1.0f - 1e-6f);
  cx = fminf(fmaxf(cx, -1.0f + 1e-6f), 1.0f - 1e-6f);
  int iy = (int)rintf(((cy + 1.0f) * (float)HF - 1.0f) * 0.5f);  // rndne == jnp.round
  int ix = (int)rintf(((cx + 1.0f) * (float)WF - 1.0f) * 0.5f);
  iy = min(max(iy, 0), HF - 1);
  ix = min(max(ix, 0), WF - 1);
  p = (iy << 6) | ix;
  rel0 = (cy0 - ((float)(2 * iy + 1) * (1.0f / HF) - 1.0f)) * (float)HF;
  rel1 = (cx0 - ((float)(2 * ix + 1) * (1.0f / WF) - 1.0f)) * (float)WF;
}

// Blend weight for tap t, query q: preds[t] pairs with areas[3-t].
__device__ __forceinline__ float blend_wt(int q, int t) {
  float a[4], tot = 0.0f;
#pragma unroll
  for (int u = 0; u < 4; ++u) {
    int p; float r0, r1;
    tap_geom(q, (u & 2) ? 1.0f : -1.0f, (u & 1) ? 1.0f : -1.0f, p, r0, r1);
    a[u] = fabsf(r0 * r1) + 1e-9f;
    tot += a[u];
  }
  float sel = (t == 0) ? a[3] : (t == 1) ? a[2] : (t == 2) ? a[1] : a[0];
  return sel / tot;
}

// One hidden layer on the shared 128-row tile, in place. R3's exact k-loop
// schedule, except: s=0's mt=0,1 A-frags arrive prefetched (apre0/1, loaded
// before the PREVIOUS barrier), and before this layer's pre-epilogue
// barrier we issue the NEXT layer's s=0 frags into apre0/1.
template <int KSTEPS, int KPAD>
__device__ __forceinline__ void mlp_layer(f16* X, const f16* __restrict__ wt,
                                          const float* __restrict__ bv,
                                          int wv, int col, int quad,
                                          f16x8& apre0, f16x8& apre1,
                                          const f16* __restrict__ nxt,
                                          int nstride) {
  f32x4 acc[4][8];
#pragma unroll
  for (int mt = 0; mt < 4; ++mt)
#pragma unroll
    for (int nt = 0; nt < 8; ++nt) acc[mt][nt] = 0.0f;

  const f16* ap = wt + (wv * 64 + col) * KPAD + quad * 8;  // A[m=col+16mt][k]
  const f16* bp = X + col * STR + quad * 8;                // B[n=col+16nt][k]

  // ---- s = 0 (peeled): mt=0,1 from prefetch; mt=2,3 inline ----
  {
    f16x8 b[8];
#pragma unroll
    for (int nt = 0; nt < 8; ++nt)
      b[nt] = *(const f16x8*)(bp + nt * 16 * STR);
#pragma unroll
    for (int nt = 0; nt < 8; ++nt) acc[0][nt] = MFMA(apre0, b[nt], acc[0][nt]);
#pragma unroll
    for (int nt = 0; nt < 8; ++nt) acc[1][nt] = MFMA(apre1, b[nt], acc[1][nt]);
#pragma unroll
    for (int mt = 2; mt < 4; ++mt) {
      f16x8 a = *(const f16x8*)(ap + mt * 16 * KPAD);
#pragma unroll
      for (int nt = 0; nt < 8; ++nt) acc[mt][nt] = MFMA(a, b[nt], acc[mt][nt]);
    }
  }
  // ---- s = 1..KSTEPS-1: identical to the proven R3 schedule ----
#pragma unroll 1
  for (int s = 1; s < KSTEPS; ++s) {
    f16x8 b[8];
#pragma unroll
    for (int nt = 0; nt < 8; ++nt)
      b[nt] = *(const f16x8*)(bp + s * 32 + nt * 16 * STR);
#pragma unroll
    for (int mt = 0; mt < 4; ++mt) {
      f16x8 a = *(const f16x8*)(ap + s * 32 + mt * 16 * KPAD);
#pragma unroll
      for (int nt = 0; nt < 8; ++nt) acc[mt][nt] = MFMA(a, b[nt], acc[mt][nt]);
    }
  }

  // Prefetch the NEXT consumer's s=0 A-frags; these global loads stay in
  // flight across the lgkm-only barriers and the epilogue (~600+cy window).
  apre0 = *(const f16x8*)(nxt);
  apre1 = *(const f16x8*)(nxt + nstride);

  bar();   // all reads of X done before overwrite (lgkm-only)
  // D: row(m=feat) = mt*16 + quad*4 + i, col(n=query) = nt*16 + col.
#pragma unroll
  for (int mt = 0; mt < 4; ++mt) {
    float4 bb = *(const float4*)(bv + wv * 64 + mt * 16 + quad * 4);
#pragma unroll
    for (int nt = 0; nt < 8; ++nt) {
      f16x4 y;
      y[0] = (f16)fmaxf(acc[mt][nt][0] + bb.x, 0.0f);
      y[1] = (f16)fmaxf(acc[mt][nt][1] + bb.y, 0.0f);
      y[2] = (f16)fmaxf(acc[mt][nt][2] + bb.z, 0.0f);
      y[3] = (f16)fmaxf(acc[mt][nt][3] + bb.w, 0.0f);
      *(f16x4*)(X + (nt * 16 + col) * STR + wv * 64 + mt * 16 + quad * 4) = y;
    }
  }
  bar();
}

__global__ __launch_bounds__(256, 2) void liif_main(
    const f16* __restrict__ featT,
    const f16* __restrict__ wt0, const f16* __restrict__ wt1,
    const f16* __restrict__ wt2, const f16* __restrict__ wt3,
    const f16* __restrict__ wt4,
    const float* __restrict__ b0, const float* __restrict__ b1,
    const float* __restrict__ b2, const float* __restrict__ b3,
    const float* __restrict__ b4, float* __restrict__ out) {
  __shared__ __attribute__((aligned(16))) f16 X[R * STR];   // 67.6 KB
  const int tid = threadIdx.x;
  const int wv = tid >> 6;
  const int lane = tid & 63;
  const int row0 = blockIdx.x * R;               // rows = n*Q + q, 128 per block
  const int n = row0 >> 16;
  const int q0 = row0 & (Q - 1);
  const int col = lane & 15, quad = lane >> 4;

  float oacc[2][4] = {{0, 0, 0, 0}, {0, 0, 0, 0}};
  float bias4[4];
#pragma unroll
  for (int i = 0; i < 4; ++i) bias4[i] = (i < 3) ? b4[i] : 0.0f;

  // Per-layer A base pointers for this thread (prefetch chain targets).
  const f16* a0b = wt0 + (wv * 64 + col) * K0P + quad * 8;
  const f16* a1b = wt1 + (wv * 64 + col) * D + quad * 8;
  const f16* a2b = wt2 + (wv * 64 + col) * D + quad * 8;
  const f16* a3b = wt3 + (wv * 64 + col) * D + quad * 8;
  const f16* a4b = wt4 + col * D + quad * 8;     // final layer (frags = s=0,1)

  // Initial prefetch: layer 0, s=0, mt=0,1.
  f16x8 apre0 = *(const f16x8*)(a0b);
  f16x8 apre1 = *(const f16x8*)(a0b + 16 * K0P);

#pragma unroll 1
  for (int t = 0; t < 4; ++t) {
    const float vx = (t & 2) ? 1.0f : -1.0f;
    const float vy = (t & 1) ? 1.0f : -1.0f;

    bar();   // previous tap's reads of X complete
    // ---- gather X0: 64 feat + rel(2) + rel_cell(2), pad to 96 ----
    {
      const int gr = tid >> 1, hf = tid & 1;   // 2 threads per row, 64 B each
      int p; float r0, r1;
      tap_geom(q0 + gr, vx, vy, p, r0, r1);
      const f16x8* src = (const f16x8*)(featT + (((size_t)n << 12) + p) * 64 + hf * 32);
      f16x8* dst = (f16x8*)(X + gr * STR + hf * 32);
      dst[0] = src[0]; dst[1] = src[1]; dst[2] = src[2]; dst[3] = src[3];
      if (tid < R) {
        int p2; float s0, s1;
        tap_geom(q0 + tid, vx, vy, p2, s0, s1);
        f16* xr = X + tid * STR;
        f16x4 relv = {(f16)s0, (f16)s1, (f16)0.5f, (f16)0.5f};
        *(f16x4*)(xr + 64) = relv;
        f16x4 z4 = {0, 0, 0, 0};
        f16x8 z8 = {0, 0, 0, 0, 0, 0, 0, 0};
        *(f16x4*)(xr + 68) = z4;     // zero pad cols 68..95
        *(f16x8*)(xr + 72) = z8;
        *(f16x8*)(xr + 80) = z8;
        *(f16x8*)(xr + 88) = z8;
      }
    }
    bar();

    mlp_layer<3, K0P>(X, wt0, b0, wv, col, quad, apre0, apre1, a1b, 16 * D);
    mlp_layer<8, D>(X, wt1, b1, wv, col, quad, apre0, apre1, a2b, 16 * D);
    mlp_layer<8, D>(X, wt2, b2, wv, col, quad, apre0, apre1, a3b, 16 * D);
    mlp_layer<8, D>(X, wt3, b3, wv, col, quad, apre0, apre1, a4b, 32);

    // ---- final layer 256 -> 16 (3 real feats); wave handles its 32 queries ----
    // s=0,1 A-frags arrive prefetched (apre0/1); s>=2 inline as before.
    f32x4 facc[2];
    facc[0] = 0.0f; facc[1] = 0.0f;
    {
      const f16* bp = X + (wv * 32 + col) * STR + quad * 8;  // B[n=query]
      f16x8 bq0 = *(const f16x8*)(bp);
      f16x8 bq1 = *(const f16x8*)(bp + 16 * STR);
      facc[0] = MFMA(apre0, bq0, facc[0]);
      facc[1] = MFMA(apre0, bq1, facc[1]);
      bq0 = *(const f16x8*)(bp + 32);
      bq1 = *(const f16x8*)(bp + 16 * STR + 32);
      facc[0] = MFMA(apre1, bq0, facc[0]);
      facc[1] = MFMA(apre1, bq1, facc[1]);
#pragma unroll 1
      for (int s = 2; s < 8; ++s) {
        f16x8 a = *(const f16x8*)(a4b + s * 32);
        f16x8 c0 = *(const f16x8*)(bp + s * 32);
        f16x8 c1 = *(const f16x8*)(bp + 16 * STR + s * 32);
        facc[0] = MFMA(a, c0, facc[0]);
        facc[1] = MFMA(a, c1, facc[1]);
      }
    }
    // D: row=feat=quad*4+i, col=query. Blend into oacc.
#pragma unroll
    for (int nt = 0; nt < 2; ++nt) {
      int q = q0 + wv * 32 + nt * 16 + col;
      float w = blend_wt(q, t);
#pragma unroll
      for (int i = 0; i < 4; ++i) oacc[nt][i] += (facc[nt][i] + bias4[i]) * w;
    }

    // Prefetch layer-0 A for the NEXT tap (crosses tap barrier + gather).
    apre0 = *(const f16x8*)(a0b);
    apre1 = *(const f16x8*)(a0b + 16 * K0P);
  }

  // out[n][c][q]; lanes with quad==0 hold feats 0..3 (3 real) for their queries
  if (quad == 0) {
#pragma unroll
    for (int nt = 0; nt < 2; ++nt) {
      int q = q0 + wv * 32 + nt * 16 + col;
#pragma unroll
      for (int c = 0; c < 3; ++c)
        out[(((size_t)(n * 3 + c)) << 16) + q] = oacc[nt][c];
    }
  }
}

extern "C" void kernel_launch(void* const* d_in, const int* in_sizes, int n_in,
                              void* d_out, int out_size, void* d_ws, size_t ws_size,
                              hipStream_t stream) {
  const float* feat = (const float*)d_in[0];
  const float* w0 = (const float*)d_in[1];
  const float* b0 = (const float*)d_in[2];
  const float* w1 = (const float*)d_in[3];
  const float* b1 = (const float*)d_in[4];
  const float* w2 = (const float*)d_in[5];
  const float* b2 = (const float*)d_in[6];
  const float* w3 = (const float*)d_in[7];
  const float* b3 = (const float*)d_in[8];
  const float* w4 = (const float*)d_in[9];
  const float* b4 = (const float*)d_in[10];

  char* ws = (char*)d_ws;
  f16* featT = (f16*)(ws + OFF_FEAT);
  f16* wt0 = (f16*)(ws + OFF_W0);
  f16* wt1 = (f16*)(ws + OFF_W1);
  f16* wt2 = (f16*)(ws + OFF_W2);
  f16* wt3 = (f16*)(ws + OFF_W3);
  f16* wt4 = (f16*)(ws + OFF_W4);

  prep_feat<<<4096, 256, 0, stream>>>(feat, featT);
  prep_w<<<(256 * 96 + 255) / 256, 256, 0, stream>>>(w0, wt0, 68, 256, 96, 256);
  prep_w<<<256, 256, 0, stream>>>(w1, wt1, 256, 256, 256, 256);
  prep_w<<<256, 256, 0, stream>>>(w2, wt2, 256, 256, 256, 256);
  prep_w<<<256, 256, 0, stream>>>(w3, wt3, 256, 256, 256, 256);
  prep_w<<<(16 * 256 + 255) / 256, 256, 0, stream>>>(w4, wt4, 256, 3, 256, 16);

  liif_main<<<Q * 4 / R, 256, 0, stream>>>(featT, wt0, wt1, wt2, wt3, wt4,
                                           b0, b1, b2, b3, b4, (float*)d_out);
}